// Round 9
// baseline (65.972 us; speedup 1.0000x reference)
//
#include <hip/hip_runtime.h>

// SoftHistLoss: x,y [16,3,512,512] f32 -> scalar f32
// hist_i = A[i] - B[i] + B[i-1] + (C[i+1] - A[i+1]);  A=sum qa/255, B=sum qb/62,
// C=count, accumulated per bin k=floor(10v) as ONE packed ds_add_u32:
//   bits[31:18] = qa = round(255*sigma(15d))   (col sum <= 64*255 = 16320)
//   bits[17: 7] = qb = round(62*sigma(15d-15)) (col sum <= 64*31  = 1984)
//   bits[ 6: 0] = 1                            (col sum <= 64)
// R8 profiling showed VALU-issue-bound (VALUBusy ~70%, 2x scaling on 2-pass).
// R9: HYBRID - even pixels fetch the packed word from a 256-entry LDS table
// (indexed by d quantized to 1/256; 8-way lane-replicated -> ~conflict-free),
// odd pixels compute it (proven R7 path). Balances VALU (~13 instr/px avg)
// against LDS pipe (1 atomic + 0.5 read per px). Loss fused via last-block
// counter (device-scope integer atomics, deterministic).

static constexpr int PLANES   = 48;               // 16*3 per image
static constexpr int PLANE_PX = 512 * 512;
static constexpr int SPP      = 16;               // sub-blocks per plane
static constexpr int THREADS  = 256;
static constexpr int CHUNK    = PLANE_PX / SPP;   // 16384 px/block, 64 px/thread
static constexpr int NBLK     = 96 * SPP;         // 1536 = 6 blocks/CU, one round
static constexpr int CTR      = 3072;             // counter word index in G
static constexpr float E15    = 3269017.3724721107f;  // e^15

__global__ __launch_bounds__(THREADS, 6) void soft_hist_fused(
    const float* __restrict__ xin, const float* __restrict__ yin,
    unsigned* __restrict__ G /* [96][30] + counter */, float* __restrict__ out)
{
  __shared__ unsigned table[256 * 8];             // 8 KB, 8 lane-copies
  __shared__ unsigned hist[10 * THREADS];         // 10 KB
  __shared__ unsigned red[10 * 16 * 3];           // 1.9 KB
  __shared__ unsigned lastflag;
  const int t = threadIdx.x;

  #pragma unroll
  for (int s = 0; s < 10; ++s) hist[s * THREADS + t] = 0u;
  {entry:
    // table entry t: packed word at d_mid = (t+0.5)/256
    float dd = ((float)t + 0.5f) * (1.0f / 256.0f);
    float ex = __expf(dd * -15.0f);
    float t1 = 1.0f + ex;
    float t2 = fmaf(E15, ex, 1.0f);
    float r  = __builtin_amdgcn_rcpf(t1 * t2);
    unsigned qa = (unsigned)fmaf(r * t2, 255.0f, 0.5f);
    unsigned qb = (unsigned)fmaf(r * t1, 62.0f, 0.5f);
    unsigned pk = (((qa << 11) + qb) << 7) + 1u;
    #pragma unroll
    for (int c = 0; c < 8; ++c) table[(t << 3) + c] = pk;
  }
  __syncthreads();

  const int blk   = blockIdx.x;
  const int plane = blk >> 4;                     // 0..95 (0..47 = x)
  const int sub   = blk & 15;
  const float* src = (plane < PLANES ? xin + (size_t)plane * PLANE_PX
                                     : yin + (size_t)(plane - PLANES) * PLANE_PX)
                   + (size_t)sub * CHUNK;
  const float4* src4 = (const float4*)src;
  const unsigned copy = (unsigned)(t & 7);

  constexpr int ITERS = CHUNK / (THREADS * 4);    // 16
  float4 c0 = src4[t];
  float4 c1 = src4[THREADS + t];
  #pragma unroll 4
  for (int it = 0; it < ITERS; ++it) {
    float4 cur = c0;
    c0 = c1;
    if (it + 2 < ITERS) c1 = src4[(it + 2) * THREADS + t];
    float vv[4] = {cur.x, cur.y, cur.z, cur.w};
    #pragma unroll
    for (int j = 0; j < 4; ++j) {
      float v = vv[j];
      if ((j & 1) == 0) {
        // table path: ~7 VALU + 1 ds_read
        unsigned u = (unsigned)(v * 2560.0f);     // bin*256 + d/256
        u = u > 2559u ? 2559u : u;
        unsigned pk = table[((u & 255u) << 3) + copy];
        atomicAdd(&hist[(u & 0xFF00u) + (unsigned)t], pk);   // ds_add_u32
      } else {
        // compute path (proven R7): ~19 VALU incl 2 trans
        float wv = v * 10.0f;
        float dd = wv - floorf(wv);
        unsigned k = (unsigned)wv;
        k = k > 9u ? 9u : k;
        float ex = __expf(dd * -15.0f);
        float t1 = 1.0f + ex;
        float t2 = fmaf(E15, ex, 1.0f);
        float r  = __builtin_amdgcn_rcpf(t1 * t2);
        unsigned qa = (unsigned)fmaf(r * t2, 255.0f, 0.5f);
        unsigned qb = (unsigned)fmaf(r * t1, 62.0f, 0.5f);
        unsigned pk = (((qa << 11) + qb) << 7) + 1u;
        atomicAdd(&hist[(k << 8) + (unsigned)t], pk);        // ds_add_u32
      }
    }
  }
  __syncthreads();

  // stage 1: 160 threads, each sums 16 columns of one bin (unpacked fields)
  if (t < 160) {
    const int bin = t >> 4, grp = t & 15;
    const uint4* hp = (const uint4*)(hist + (bin << 8) + (grp << 4));
    unsigned sa = 0, sb = 0, sc = 0;
    #pragma unroll
    for (int q = 0; q < 4; ++q) {
      uint4 u4 = hp[q];
      unsigned uu[4] = {u4.x, u4.y, u4.z, u4.w};
      #pragma unroll
      for (int e = 0; e < 4; ++e) {
        unsigned u = uu[e];
        sa += u >> 18; sb += (u >> 7) & 0x7FFu; sc += u & 0x7Fu;
      }
    }
    const int base = (bin * 16 + grp) * 3;
    red[base] = sa; red[base + 1] = sb; red[base + 2] = sc;
  }
  __syncthreads();

  // stage 2: 30 threads -> global integer atomics (deterministic)
  if (t < 30) {
    const int bin = t / 3, c = t - 3 * bin;
    unsigned s = 0;
    #pragma unroll
    for (int g = 0; g < 16; ++g) s += red[(bin * 16 + g) * 3 + c];
    atomicAdd(&G[plane * 30 + bin * 3 + c], s);
  }
  __syncthreads();

  // fused loss: last block to finish computes the scalar
  if (t == 0) {
    __threadfence();                              // release my G updates
    unsigned old = atomicAdd(&G[CTR], 1u);
    lastflag = (old == (unsigned)(NBLK - 1)) ? 1u : 0u;
  }
  __syncthreads();
  if (lastflag != 0u) {
    __threadfence();                              // acquire all G updates
    float val = 0.0f;
    for (int item = t; item < 480; item += THREADS) {
      const int pc = item / 10, i = item - pc * 10;
      const unsigned* gx = G + pc * 30;
      const unsigned* gy = G + (pc + PLANES) * 30;
      float hx = (float)gx[3 * i] * (1.0f / 255.0f)
               - (float)gx[3 * i + 1] * (1.0f / 62.0f)
               + (i > 0 ? (float)gx[3 * (i - 1) + 1] * (1.0f / 62.0f) : 0.0f)
               + (i < 9 ? (float)gx[3 * (i + 1) + 2]
                        - (float)gx[3 * (i + 1)] * (1.0f / 255.0f) : 0.0f);
      float hy = (float)gy[3 * i] * (1.0f / 255.0f)
               - (float)gy[3 * i + 1] * (1.0f / 62.0f)
               + (i > 0 ? (float)gy[3 * (i - 1) + 1] * (1.0f / 62.0f) : 0.0f)
               + (i < 9 ? (float)gy[3 * (i + 1) + 2]
                        - (float)gy[3 * (i + 1)] * (1.0f / 255.0f) : 0.0f);
      val += fabsf(hx - hy);
    }
    #pragma unroll
    for (int off = 32; off >= 1; off >>= 1) val += __shfl_xor(val, off, 64);
    float* fred = (float*)red;
    if ((t & 63) == 0) fred[t >> 6] = val;
    __syncthreads();
    if (t == 0)
      out[0] = (fred[0] + fred[1] + fred[2] + fred[3]) * 6.25e-7f;
    // G[CTR] re-zeroed by next call's memset
  }
}

extern "C" void kernel_launch(void* const* d_in, const int* in_sizes, int n_in,
                              void* d_out, int out_size, void* d_ws, size_t ws_size,
                              hipStream_t stream) {
  const float* x = (const float*)d_in[0];
  const float* y = (const float*)d_in[1];
  unsigned* G = (unsigned*)d_ws;               // 2880 words + counter @3072
  hipMemsetAsync(d_ws, 0, (CTR + 1) * sizeof(unsigned), stream);
  soft_hist_fused<<<NBLK, THREADS, 0, stream>>>(x, y, G, (float*)d_out);
}

// Round 10
// 30.439 us; speedup vs baseline: 2.1673x; 2.1673x over previous
//
#include <hip/hip_runtime.h>

// SoftHistLoss: x,y [16,3,512,512] f32 -> scalar f32
// hist_i = A[i] - B[i] + B[i-1] + (C[i+1] - A[i+1]); A=sum qa/255, B=sum qb/62,
// C=count, accumulated at bin k=floor(10v) as ONE packed ds_add_u32:
//   bits[31:18] qa  (col sum <= 64*255 = 16320 < 2^14)
//   bits[17: 7] qb  (col sum <= 64*31  = 1984  < 2^11)
//   bits[ 6: 0] 1   (col sum <= 64            < 2^7)
// R10 single-sigmoid refactor: with m = 0.5 - |d-0.5| and s = sigma(-15m),
//   d <  0.5:  qa = 255 - trunc(255 s), qb = 0          (far side saturates)
//   d >= 0.5:  qa = 255,                qb = trunc(62 s)
// both realized branchlessly as pk = BASE + (qs << sel), qs = trunc(s*scale),
// scale = lo ? -255 : 62, sel = lo ? 18 : 7, BASE = (255<<18)+1.
// (R8 profiling: VALU-issue-bound at ~70% busy -> cut ~5 VALU ops/px.)
// (R9 lesson: NO dependent LDS reads in the pixel loop - atomics only.)

static constexpr int PLANES   = 48;               // 16*3 per image
static constexpr int PLANE_PX = 512 * 512;
static constexpr int SPP      = 16;               // sub-blocks per plane
static constexpr int THREADS  = 256;
static constexpr int CHUNK    = PLANE_PX / SPP;   // 16384 px/block, 64 px/thread
static constexpr int NBLK     = 96 * SPP;         // 1536 = 6 blocks/CU, one round
static constexpr unsigned BASE = (255u << 18) + 1u;

__global__ __launch_bounds__(THREADS, 6) void soft_hist_partial(
    const float* __restrict__ xin, const float* __restrict__ yin,
    unsigned* __restrict__ G /* [96][30] u32: per plane {A,B,C} x 10 bins */)
{
  __shared__ unsigned hist[11 * THREADS];         // 11264 B (row 10 = pad for v==1.0)
  __shared__ unsigned red[10 * 16 * 3];           // 1920 B
  const int t = threadIdx.x;
  #pragma unroll
  for (int s = 0; s < 11; ++s) hist[s * THREADS + t] = 0u;
  __syncthreads();

  const int blk   = blockIdx.x;
  const int plane = blk >> 4;                     // 0..95 (0..47 = x, 48..95 = y)
  const int sub   = blk & 15;
  const float* src = (plane < PLANES ? xin + (size_t)plane * PLANE_PX
                                     : yin + (size_t)(plane - PLANES) * PLANE_PX)
                   + (size_t)sub * CHUNK;
  const float4* src4 = (const float4*)src;
  unsigned* mycol = hist + t;

  constexpr int ITERS = CHUNK / (THREADS * 4);    // 16
  float4 c0 = src4[t];
  float4 c1 = src4[THREADS + t];
  #pragma unroll 4
  for (int it = 0; it < ITERS; ++it) {
    float4 cur = c0;
    c0 = c1;
    if (it + 2 < ITERS) c1 = src4[(it + 2) * THREADS + t];
    float vv[4] = {cur.x, cur.y, cur.z, cur.w};
    #pragma unroll
    for (int j = 0; j < 4; ++j) {
      float W  = vv[j] * 10.0f;                   // [0,10]
      unsigned k = (unsigned)W;                   // trunc; k=10 -> pad row
      float d  = W - floorf(W);                   // v_fract
      float mp = d - 0.5f;
      bool lo  = mp < 0.0f;
      // s = sigma(-15*(0.5-|mp|)) = 1/(1+e^{15m}), arg = 7.5 - 15|mp|
      float ex = __expf(fmaf(-15.0f, fabsf(mp), 7.5f));
      float sg = __builtin_amdgcn_rcpf(1.0f + ex);
      float scale = lo ? -255.0f : 62.0f;
      int   qs = (int)(sg * scale);               // trunc toward 0
      unsigned sel = lo ? 18u : 7u;
      unsigned pk  = ((unsigned)qs << sel) + BASE;
      atomicAdd(&mycol[k << 8], pk);              // ds_add_u32, fire-and-forget
    }
  }
  __syncthreads();

  // stage 1: 160 threads, each sums 16 columns of one bin (unpacked fields)
  if (t < 160) {
    const int bin = t >> 4, grp = t & 15;
    const uint4* hp = (const uint4*)(hist + (bin << 8) + (grp << 4));
    unsigned sa = 0, sb = 0, sc = 0;
    #pragma unroll
    for (int q = 0; q < 4; ++q) {
      uint4 u4 = hp[q];
      unsigned uu[4] = {u4.x, u4.y, u4.z, u4.w};
      #pragma unroll
      for (int e = 0; e < 4; ++e) {
        unsigned u = uu[e];
        sa += u >> 18; sb += (u >> 7) & 0x7FFu; sc += u & 0x7Fu;
      }
    }
    const int base = (bin * 16 + grp) * 3;
    red[base] = sa; red[base + 1] = sb; red[base + 2] = sc;
  }
  __syncthreads();

  // stage 2: 30 threads -> global integer atomics (deterministic)
  if (t < 30) {
    const int bin = t / 3, c = t - 3 * bin;
    unsigned s = 0;
    #pragma unroll
    for (int g = 0; g < 16; ++g) s += red[(bin * 16 + g) * 3 + c];
    atomicAdd(&G[plane * 30 + bin * 3 + c], s);
  }
}

__global__ __launch_bounds__(512) void soft_hist_loss(
    const unsigned* __restrict__ G, float* __restrict__ out)
{
  __shared__ float wred[8];
  const int t = threadIdx.x;
  float val = 0.0f;
  if (t < 480) {
    const int pc = t / 10;        // (batch,channel) 0..47
    const int i  = t - pc * 10;   // bin
    const unsigned* gx = G + pc * 30;
    const unsigned* gy = G + (pc + PLANES) * 30;
    // hist_i = A[i]/255 - B[i]/62 + B[i-1]/62 + C[i+1] - A[i+1]/255
    float hx = (float)gx[3 * i] * (1.0f / 255.0f)
             - (float)gx[3 * i + 1] * (1.0f / 62.0f)
             + (i > 0 ? (float)gx[3 * (i - 1) + 1] * (1.0f / 62.0f) : 0.0f)
             + (i < 9 ? (float)gx[3 * (i + 1) + 2]
                      - (float)gx[3 * (i + 1)] * (1.0f / 255.0f) : 0.0f);
    float hy = (float)gy[3 * i] * (1.0f / 255.0f)
             - (float)gy[3 * i + 1] * (1.0f / 62.0f)
             + (i > 0 ? (float)gy[3 * (i - 1) + 1] * (1.0f / 62.0f) : 0.0f)
             + (i < 9 ? (float)gy[3 * (i + 1) + 2]
                      - (float)gy[3 * (i + 1)] * (1.0f / 255.0f) : 0.0f);
    val = fabsf(hx - hy);
  }
  #pragma unroll
  for (int off = 32; off >= 1; off >>= 1) val += __shfl_xor(val, off, 64);
  if ((t & 63) == 0) wred[t >> 6] = val;
  __syncthreads();
  if (t == 0) {
    float s = 0.0f;
    #pragma unroll
    for (int w = 0; w < 8; ++w) s += wred[w];
    // loss = sum * (1/BINS) * (1/B) * 1e-4
    out[0] = s * 6.25e-7f;
  }
}

extern "C" void kernel_launch(void* const* d_in, const int* in_sizes, int n_in,
                              void* d_out, int out_size, void* d_ws, size_t ws_size,
                              hipStream_t stream) {
  const float* x = (const float*)d_in[0];
  const float* y = (const float*)d_in[1];
  unsigned* G = (unsigned*)d_ws;               // 96*30*4 = 11520 B
  hipMemsetAsync(d_ws, 0, 96 * 30 * sizeof(unsigned), stream);
  soft_hist_partial<<<NBLK, THREADS, 0, stream>>>(x, y, G);
  soft_hist_loss<<<1, 512, 0, stream>>>(G, (float*)d_out);
}